// Round 2
// baseline (1396.203 us; speedup 1.0000x reference)
//
#include <hip/hip_runtime.h>

// Problem constants (B, H, W) from the reference.
#define BB 8
#define HH 1080
#define WW 1920
constexpr int HWc  = HH * WW;          // 2,073,600
constexpr int Ntot = BB * HWc;         // 16,588,800

constexpr int TILE = 64;               // OUTPUT core side (exclusive per block)
constexpr int MAR  = 32;               // gather margin: P(|N(0,10)| > 32) ~ 7e-4 per tail
constexpr int REG  = TILE + 2 * MAR;   // 128 -> source region 128x128
constexpr int WT   = WW / TILE;        // 30 (exact)
constexpr int HT   = (HH + TILE - 1) / TILE;  // 17 (last core partial: rows 1024..1079)
constexpr int NTILE = WT * HT;         // 510 tiles per image
constexpr int CELLS = TILE * TILE;     // 4096 cells per channel plane

static_assert(TILE == 64, "ownership test uses >>6");
static_assert((WW & 3) == 0 && (HWc & 3) == 0, "float4 groups must not straddle");

// Workspace: 3 planar channels {sum(-fx*w), sum(-fy*w), sum(w)}, each Ntot floats
// (199 MB). Optional per-tile dirty flags (NTILE*BB ints) appended IF ws_size
// permits — checked at runtime in kernel_launch, else flags==nullptr and every
// tile merges (correct either way).

// ---------------------------------------------------------------------------
// Pre-pass: the RARE corners whose SOURCE lies outside the gather region of the
// corner's OWNER tile (|flow| beyond margin). Global atomics into acc, BEFORE
// tile_k, so they never race with tile_k's exclusive non-atomic writeback.
// Fast path: if max|fx|,|fy| over the 4-pixel group <= 30, every corner is
// provably in-region (|corner - x| <= |fx|+1 <= 31 <= margin-1) -> exit.
// ---------------------------------------------------------------------------
__global__ __launch_bounds__(256) void prepass_k(const float* __restrict__ flow,
                                                 const float* __restrict__ depth,
                                                 float* __restrict__ acc,
                                                 int* __restrict__ flags) {
    constexpr int NG = Ntot / 4;
    int g = blockIdx.x * 256 + threadIdx.x;
    if (g >= NG) return;
    int idx = g << 2;
    int b = idx / HWc;
    int p = idx - b * HWc;          // multiple of 4; rows aligned (WW%4==0)
    int y = p / WW;
    int x = p - y * WW;

    const size_t fbase = (size_t)b * 2 * HWc;
    float4 fx4 = *(const float4*)(flow + fbase + p);
    float4 fy4 = *(const float4*)(flow + fbase + HWc + p);

    float m = fmaxf(fmaxf(fmaxf(fabsf(fx4.x), fabsf(fx4.y)),
                          fmaxf(fabsf(fx4.z), fabsf(fx4.w))),
                    fmaxf(fmaxf(fabsf(fy4.x), fabsf(fy4.y)),
                          fmaxf(fabsf(fy4.z), fabsf(fy4.w))));
    if (m <= 30.f) return;          // ~98% of lanes exit here

    const float fxs[4] = {fx4.x, fx4.y, fx4.z, fx4.w};
    const float fys[4] = {fy4.x, fy4.y, fy4.z, fy4.w};
    float* a0 = acc + (size_t)b * HWc;
    float* a1 = acc + (size_t)Ntot + (size_t)b * HWc;
    float* a2 = acc + (size_t)2 * Ntot + (size_t)b * HWc;

#pragma unroll
    for (int c = 0; c < 4; ++c) {
        float fx = fxs[c], fy = fys[c];
        int xs = x + c;
        float x2 = (float)xs + fx;
        float y2 = (float)y + fy;
        if (!(x2 >= 0.f && x2 <= (float)(WW - 1) && y2 >= 0.f && y2 <= (float)(HH - 1)))
            continue;
        int ixL = min(max((int)floorf(x2), 0), WW - 1);
        int iyT = min(max((int)floorf(y2), 0), HH - 1);
        int ixR = min(ixL + 1, WW - 1);
        int iyB = min(iyT + 1, HH - 1);
        int cxs[2] = {ixL, ixR};
        int cys[2] = {iyT, iyB};
        bool anyOut = false;
#pragma unroll
        for (int a = 0; a < 2; ++a)
#pragma unroll
            for (int cc = 0; cc < 2; ++cc) {
                int cx = cxs[cc], cy = cys[a];
                int ox = (cx >> 6) * TILE - MAR;
                int oy = (cy >> 6) * TILE - MAR;
                if (!(xs >= ox && xs < ox + REG && y >= oy && y < oy + REG))
                    anyOut = true;
            }
        if (!anyOut) continue;

        float w = depth[(size_t)b * HWc + p + c];
        float vx = -fx * w;
        float vy = -fy * w;
#pragma unroll
        for (int a = 0; a < 2; ++a)
#pragma unroll
            for (int cc = 0; cc < 2; ++cc) {
                int cx = cxs[cc], cy = cys[a];
                int ox = (cx >> 6) * TILE - MAR;
                int oy = (cy >> 6) * TILE - MAR;
                if (!(xs >= ox && xs < ox + REG && y >= oy && y < oy + REG)) {
                    int q = cy * WW + cx;
                    atomicAdd(a0 + q, vx);
                    atomicAdd(a1 + q, vy);
                    atomicAdd(a2 + q, w);
                    if (flags)
                        flags[(size_t)b * NTILE + (cy >> 6) * WT + (cx >> 6)] = 1;
                }
            }
    }
}

// ---------------------------------------------------------------------------
// Gather-tile kernel: one block (512 threads) per EXCLUSIVE 64x64 output core.
// Reads the 128x128 source neighborhood with float4 loads + 1-deep register
// prefetch, splats all 3 channels into 48 KB LDS, then race-free writeback:
// merge prepass acc (skipped when the tile's dirty flag is clear), divide,
// write out (2 planes) + count plane. 48 KB LDS + <=80 VGPR -> 3 blocks/CU
// = 24 waves/CU (75%).
// ---------------------------------------------------------------------------
#define PROC(FXC, FYC, DWC, CGX)                                               \
    {                                                                          \
        float fx = (FXC), fy = (FYC);                                          \
        float x2 = (float)(CGX) + fx, y2 = gyf + fy;                           \
        if (x2 >= 0.f && x2 <= (float)(WW - 1) &&                              \
            y2 >= 0.f && y2 <= (float)(HH - 1)) {                              \
            int ixL = min(max((int)floorf(x2), 0), WW - 1);                    \
            int iyT = min(max((int)floorf(y2), 0), HH - 1);                    \
            int ixR = min(ixL + 1, WW - 1);                                    \
            int iyB = min(iyT + 1, HH - 1);                                    \
            if (ixR >= X0 && ixL < X0 + TILE &&                                \
                iyB >= Y0 && iyT < Y0 + TILE) {                                \
                float w = (DWC);                                               \
                float vx = -fx * w, vy = -fy * w;                              \
                int cxs[2] = {ixL, ixR};                                       \
                int cys[2] = {iyT, iyB};                                       \
                _Pragma("unroll")                                              \
                for (int a = 0; a < 2; ++a) {                                  \
                    _Pragma("unroll")                                          \
                    for (int c2 = 0; c2 < 2; ++c2) {                           \
                        unsigned ux = (unsigned)(cxs[c2] - X0);                \
                        unsigned uy = (unsigned)(cys[a] - Y0);                 \
                        if (ux < (unsigned)TILE && uy < (unsigned)TILE) {      \
                            int cell = (int)((uy << 6) + ux);                  \
                            atomicAdd(&sm[cell], vx);                          \
                            atomicAdd(&sm[cell + CELLS], vy);                  \
                            atomicAdd(&sm[cell + 2 * CELLS], w);               \
                        }                                                      \
                    }                                                          \
                }                                                              \
            }                                                                  \
        }                                                                      \
    }

__global__ __launch_bounds__(512, 6) void tile_k(const float* __restrict__ flow,
                                                 const float* __restrict__ depth,
                                                 float* acc,   // plane2 read+write
                                                 float* __restrict__ out,
                                                 const int* __restrict__ flags) {
    __shared__ float sm[3 * CELLS];    // 48 KB
    const int bid  = blockIdx.x;
    const int b    = bid & 7;          // image round-robin (XCD affinity heuristic)
    const int tile = bid >> 3;
    const int ty   = tile / WT;
    const int tx   = tile - ty * WT;
    const int X0 = tx * TILE, Y0 = ty * TILE;
    const int rx0 = X0 - MAR, ry0 = Y0 - MAR;
    const int tid = threadIdx.x;

    // zero LDS: 3072 float4 / 512 threads = 6 per thread
    float4* sm4 = (float4*)sm;
#pragma unroll
    for (int k = 0; k < 6; ++k)
        sm4[k * 512 + tid] = make_float4(0.f, 0.f, 0.f, 0.f);
    __syncthreads();

    const float* fxp = flow + (size_t)b * 2 * HWc;
    const float* fyp = fxp + HWc;
    const float* dp  = depth + (size_t)b * HWc;

    // splat: 8 iterations; each thread owns a fixed 4-pixel column group and
    // walks 16 rows/iter. float4 loads; 1-deep register prefetch pipeline.
    const int gx  = rx0 + ((tid & 31) << 2);   // group start (4-aligned)
    const bool xok = (unsigned)gx < (unsigned)WW;  // groups fully in/out in x
    int gy = ry0 + (tid >> 5);
    float4 cfx, cfy, cd;
    bool ok = xok && ((unsigned)gy < (unsigned)HH);
    if (ok) {
        int p = gy * WW + gx;
        cfx = *(const float4*)(fxp + p);
        cfy = *(const float4*)(fyp + p);
        cd  = *(const float4*)(dp + p);
    }
#pragma unroll
    for (int k = 0; k < 8; ++k) {
        float4 nfx, nfy, nd;
        bool nok = false;
        const int ngy = gy + 16;
        if (k < 7) {
            nok = xok && ((unsigned)ngy < (unsigned)HH);
            if (nok) {
                int np = ngy * WW + gx;
                nfx = *(const float4*)(fxp + np);
                nfy = *(const float4*)(fyp + np);
                nd  = *(const float4*)(dp + np);
            }
        }
        if (ok) {
            const float gyf = (float)gy;
            PROC(cfx.x, cfy.x, cd.x, gx)
            PROC(cfx.y, cfy.y, cd.y, gx + 1)
            PROC(cfx.z, cfy.z, cd.z, gx + 2)
            PROC(cfx.w, cfy.w, cd.w, gx + 3)
        }
        ok = nok; gy = ngy; cfx = nfx; cfy = nfy; cd = nd;
    }
    __syncthreads();

    // exclusive writeback fused with average. merge flag is block-uniform.
    bool merge = true;
    if (flags) merge = (flags[(size_t)b * NTILE + tile] != 0);

    const float* a0 = acc + (size_t)b * HWc;
    const float* a1 = acc + (size_t)Ntot + (size_t)b * HWc;
    float*       a2 = acc + (size_t)2 * Ntot + (size_t)b * HWc;
    float* o0 = out + (size_t)b * 2 * HWc;
    float* o1 = o0 + HWc;
#pragma unroll
    for (int k = 0; k < 2; ++k) {              // 1024 float4 groups / 512 threads
        int j  = k * 512 + tid;
        int gy2 = Y0 + (j >> 4);
        if (gy2 < HH) {
            int q = gy2 * WW + X0 + ((j & 15) << 2);
            float4 vx = sm4[j];
            float4 vy = sm4[j + CELLS / 4];
            float4 wv = sm4[j + 2 * CELLS / 4];
            if (merge) {
                float4 e0 = *(const float4*)(a0 + q);
                float4 e1 = *(const float4*)(a1 + q);
                float4 e2 = *(const float4*)(a2 + q);
                vx.x += e0.x; vx.y += e0.y; vx.z += e0.z; vx.w += e0.w;
                vy.x += e1.x; vy.y += e1.y; vy.z += e1.z; vy.w += e1.w;
                wv.x += e2.x; wv.y += e2.y; wv.z += e2.z; wv.w += e2.w;
            }
            float i0 = wv.x > 0.f ? 1.f / wv.x : 0.f;
            float i1 = wv.y > 0.f ? 1.f / wv.y : 0.f;
            float i2 = wv.z > 0.f ? 1.f / wv.z : 0.f;
            float i3 = wv.w > 0.f ? 1.f / wv.w : 0.f;
            float4 r0, r1;
            r0.x = vx.x * i0; r0.y = vx.y * i1; r0.z = vx.z * i2; r0.w = vx.w * i3;
            r1.x = vy.x * i0; r1.y = vy.y * i1; r1.z = vy.z * i2; r1.w = vy.w * i3;
            *(float4*)(o0 + q) = r0;
            *(float4*)(o1 + q) = r1;
            *(float4*)(a2 + q) = wv;   // final count for fill_k
        }
    }
}

// ---------------------------------------------------------------------------
// Hole fill: for count==0 pixels, average nearest filled pixel in each of the
// 4 axis directions. Reads only filled pixels, writes only holes.
// ---------------------------------------------------------------------------
__global__ __launch_bounds__(256) void fill_k(float* __restrict__ out,
                                              const float* __restrict__ cw) {
    int idx = blockIdx.x * 256 + threadIdx.x;
    if (idx >= Ntot) return;
    if (cw[idx] > 0.f) return;

    int b = idx / HWc;
    int p = idx - b * HWc;
    int y = p / WW;
    int x = p - y * WW;

    const float* cb = cw + (size_t)b * HWc;
    const float* o0 = out + (size_t)b * 2 * HWc;
    const float* o1 = o0 + HWc;

    float s = 0.f, s0 = 0.f, s1 = 0.f;
    for (int j = x - 1; j >= 0; --j) {
        int q = y * WW + j;
        if (cb[q] > 0.f) { s += 1.f; s0 += o0[q]; s1 += o1[q]; break; }
    }
    for (int j = x + 1; j < WW; ++j) {
        int q = y * WW + j;
        if (cb[q] > 0.f) { s += 1.f; s0 += o0[q]; s1 += o1[q]; break; }
    }
    for (int i = y - 1; i >= 0; --i) {
        int q = i * WW + x;
        if (cb[q] > 0.f) { s += 1.f; s0 += o0[q]; s1 += o1[q]; break; }
    }
    for (int i = y + 1; i < HH; ++i) {
        int q = i * WW + x;
        if (cb[q] > 0.f) { s += 1.f; s0 += o0[q]; s1 += o1[q]; break; }
    }

    if (s > 0.f) {
        ((float*)o0)[p] = s0 / s;
        ((float*)o1)[p] = s1 / s;
    }
}

extern "C" void kernel_launch(void* const* d_in, const int* in_sizes, int n_in,
                              void* d_out, int out_size, void* d_ws, size_t ws_size,
                              hipStream_t stream) {
    const float* flow  = (const float*)d_in[0];   // (B,2,H,W)
    const float* depth = (const float*)d_in[1];   // (B,1,H,W)
    float* out = (float*)d_out;                   // (B,2,H,W)
    float* acc = (float*)d_ws;                    // 3 planes x Ntot floats = 199 MB

    const size_t accBytes  = (size_t)3 * Ntot * sizeof(float);
    const size_t flagBytes = (size_t)NTILE * BB * sizeof(int);
    int* flags = nullptr;
    if (ws_size >= accBytes + flagBytes)
        flags = (int*)((char*)d_ws + accBytes);

    const int threads = 256;
    const int grid1d = (Ntot + threads - 1) / threads;

    // zero the accumulator (+ flags if present) — graph-capture-safe
    hipMemsetAsync(acc, 0, accBytes, stream);
    if (flags) hipMemsetAsync(flags, 0, flagBytes, stream);

    // rare far-flung corners via global atomics (must precede tile_k)
    prepass_k<<<(Ntot / 4 + threads - 1) / threads, threads, 0, stream>>>(
        flow, depth, acc, flags);

    // single launch: exclusive output tiles, fused splat+merge+average
    tile_k<<<NTILE * BB, 512, 0, stream>>>(flow, depth, acc, out, flags);

    fill_k<<<grid1d, threads, 0, stream>>>(out, acc + (size_t)2 * Ntot);
}

// Round 3
// 690.568 us; speedup vs baseline: 2.0218x; 2.0218x over previous
//
#include <hip/hip_runtime.h>

// Problem constants (B, H, W) from the reference.
#define BB 8
#define HH 1080
#define WW 1920
constexpr int HWc  = HH * WW;          // 2,073,600
constexpr int Ntot = BB * HWc;         // 16,588,800

constexpr int TILE = 64;               // OUTPUT core side (exclusive per block)
constexpr int MAR  = 32;               // gather margin: P(|N(0,10)| > 32) ~ 7e-4 per tail
constexpr int REG  = TILE + 2 * MAR;   // 128 -> source region 128x128
constexpr int WT   = WW / TILE;        // 30 (exact)
constexpr int HT   = (HH + TILE - 1) / TILE;  // 17 (last core partial: rows 1024..1079)
constexpr int NTILE = WT * HT;         // 510 tiles per image

// S-plane: corner-anchor accumulator. S[r][c] holds sum of v over sources whose
// top-left corner (iyT,ixL) = (Y0-1+r, X0-1+c). Output cell = 2x2 box of S.
constexpr int SDIM = 65;               // rows/cols Y0-1 .. Y0+63
constexpr int SSTR = 66;               // stride (row step shifts banks by 2)
constexpr int PL   = SSTR * SSTR;      // 4356 floats per channel plane
// LDS: 3 * 4356 * 4 = 52,272 B -> 3 blocks/CU (156.8 KB of 160 KB)

static_assert(TILE == 64, "ownership test uses >>6");
static_assert((WW & 3) == 0 && (HWc & 3) == 0, "float4 groups must not straddle");
static_assert(3 * PL * 4 <= 53000, "need 3 blocks/CU");

// ---------------------------------------------------------------------------
// Pre-pass: the RARE corners whose SOURCE lies outside the gather window of the
// corner's OWNER tile (|flow| beyond margin). Global atomics into acc (final
// corner semantics, duplicates double-added like the reference), BEFORE tile_k.
// Fast path: if max|fx|,|fy| over the 4-pixel group <= 30, every corner is
// provably in-window -> exit.
// ---------------------------------------------------------------------------
__global__ __launch_bounds__(256) void prepass_k(const float* __restrict__ flow,
                                                 const float* __restrict__ depth,
                                                 float* __restrict__ acc,
                                                 int* __restrict__ flags) {
    constexpr int NG = Ntot / 4;
    int g = blockIdx.x * 256 + threadIdx.x;
    if (g >= NG) return;
    int idx = g << 2;
    int b = idx / HWc;
    int p = idx - b * HWc;          // multiple of 4; rows aligned (WW%4==0)
    int y = p / WW;
    int x = p - y * WW;

    const size_t fbase = (size_t)b * 2 * HWc;
    float4 fx4 = *(const float4*)(flow + fbase + p);
    float4 fy4 = *(const float4*)(flow + fbase + HWc + p);

    float m = fmaxf(fmaxf(fmaxf(fabsf(fx4.x), fabsf(fx4.y)),
                          fmaxf(fabsf(fx4.z), fabsf(fx4.w))),
                    fmaxf(fmaxf(fabsf(fy4.x), fabsf(fy4.y)),
                          fmaxf(fabsf(fy4.z), fabsf(fy4.w))));
    if (m <= 30.f) return;          // ~98% of lanes exit here

    const float fxs[4] = {fx4.x, fx4.y, fx4.z, fx4.w};
    const float fys[4] = {fy4.x, fy4.y, fy4.z, fy4.w};
    float* a0 = acc + (size_t)b * HWc;
    float* a1 = acc + (size_t)Ntot + (size_t)b * HWc;
    float* a2 = acc + (size_t)2 * Ntot + (size_t)b * HWc;

#pragma unroll
    for (int c = 0; c < 4; ++c) {
        float fx = fxs[c], fy = fys[c];
        int xs = x + c;
        float x2 = (float)xs + fx;
        float y2 = (float)y + fy;
        if (!(x2 >= 0.f && x2 <= (float)(WW - 1) && y2 >= 0.f && y2 <= (float)(HH - 1)))
            continue;
        int ixL = min(max((int)floorf(x2), 0), WW - 1);
        int iyT = min(max((int)floorf(y2), 0), HH - 1);
        int ixR = min(ixL + 1, WW - 1);
        int iyB = min(iyT + 1, HH - 1);
        int cxs[2] = {ixL, ixR};
        int cys[2] = {iyT, iyB};
        bool anyOut = false;
#pragma unroll
        for (int a = 0; a < 2; ++a)
#pragma unroll
            for (int cc = 0; cc < 2; ++cc) {
                int cx = cxs[cc], cy = cys[a];
                int ox = (cx >> 6) * TILE - MAR;
                int oy = (cy >> 6) * TILE - MAR;
                if (!(xs >= ox && xs < ox + REG && y >= oy && y < oy + REG))
                    anyOut = true;
            }
        if (!anyOut) continue;

        float w = depth[(size_t)b * HWc + p + c];
        float vx = -fx * w;
        float vy = -fy * w;
#pragma unroll
        for (int a = 0; a < 2; ++a)
#pragma unroll
            for (int cc = 0; cc < 2; ++cc) {
                int cx = cxs[cc], cy = cys[a];
                int ox = (cx >> 6) * TILE - MAR;
                int oy = (cy >> 6) * TILE - MAR;
                if (!(xs >= ox && xs < ox + REG && y >= oy && y < oy + REG)) {
                    int q = cy * WW + cx;
                    atomicAdd(a0 + q, vx);
                    atomicAdd(a1 + q, vy);
                    atomicAdd(a2 + q, w);
                    if (flags)
                        flags[(size_t)b * NTILE + (cy >> 6) * WT + (cx >> 6)] = 1;
                }
            }
    }
}

// ---------------------------------------------------------------------------
// Gather-tile kernel: one block (512 threads) per EXCLUSIVE 64x64 output core.
// Reads the 128x128 source window (float4 + 1-deep prefetch), splats each
// valid source ONCE (3 LDS atomics, was 12) into the S-plane at its top-left
// corner anchor (iyT,ixL) — clamp-duplicates handled by scaling ×2 per clamped
// axis — then reconstructs every output cell as the 2x2 box sum of S during
// the race-free writeback (merge prepass acc if dirty, divide, store out +
// count plane).
// ---------------------------------------------------------------------------
#define PROC(FXC, FYC, DWC, CGX)                                               \
    {                                                                          \
        float fx = (FXC), fy = (FYC);                                          \
        float x2 = (float)(CGX) + fx, y2 = gyf + fy;                           \
        if (x2 >= 0.f && x2 <= (float)(WW - 1) &&                              \
            y2 >= 0.f && y2 <= (float)(HH - 1)) {                              \
            int ixL = min(max((int)floorf(x2), 0), WW - 1);                    \
            int iyT = min(max((int)floorf(y2), 0), HH - 1);                    \
            unsigned cI = (unsigned)(ixL - (X0 - 1));                          \
            unsigned rI = (unsigned)(iyT - (Y0 - 1));                          \
            if (cI < (unsigned)SDIM && rI < (unsigned)SDIM) {                  \
                float w = (DWC);                                               \
                if (ixL == WW - 1) w += w;   /* duplicate corner: x clamp */   \
                if (iyT == HH - 1) w += w;   /* duplicate corner: y clamp */   \
                int cell = (int)(rI * SSTR + cI);                              \
                atomicAdd(&sm[cell],          -fx * w);                        \
                atomicAdd(&sm[cell + PL],     -fy * w);                        \
                atomicAdd(&sm[cell + 2 * PL], w);                              \
            }                                                                  \
        }                                                                      \
    }

__global__ __launch_bounds__(512, 6) void tile_k(const float* __restrict__ flow,
                                                 const float* __restrict__ depth,
                                                 float* acc,   // plane2 read+write
                                                 float* __restrict__ out,
                                                 const int* __restrict__ flags) {
    __shared__ float sm[3 * PL];       // 52.3 KB
    const int bid  = blockIdx.x;
    const int b    = bid & 7;          // image round-robin (XCD affinity heuristic)
    const int tile = bid >> 3;
    const int ty   = tile / WT;
    const int tx   = tile - ty * WT;
    const int X0 = tx * TILE, Y0 = ty * TILE;
    const int rx0 = X0 - MAR, ry0 = Y0 - MAR;
    const int tid = threadIdx.x;

    // zero LDS: 3267 float4 / 512 threads
    float4* sm4 = (float4*)sm;
    for (int i = tid; i < 3 * PL / 4; i += 512)
        sm4[i] = make_float4(0.f, 0.f, 0.f, 0.f);
    __syncthreads();

    const float* fxp = flow + (size_t)b * 2 * HWc;
    const float* fyp = fxp + HWc;
    const float* dp  = depth + (size_t)b * HWc;

    // splat: 8 iterations; each thread owns a fixed 4-pixel column group and
    // walks 16 rows/iter. float4 loads; 1-deep register prefetch pipeline.
    const int gx  = rx0 + ((tid & 31) << 2);       // group start (4-aligned)
    const bool xok = (unsigned)gx < (unsigned)WW;  // groups fully in/out in x
    int gy = ry0 + (tid >> 5);
    float4 cfx, cfy, cd;
    bool ok = xok && ((unsigned)gy < (unsigned)HH);
    if (ok) {
        int p = gy * WW + gx;
        cfx = *(const float4*)(fxp + p);
        cfy = *(const float4*)(fyp + p);
        cd  = *(const float4*)(dp + p);
    }
#pragma unroll
    for (int k = 0; k < 8; ++k) {
        float4 nfx, nfy, nd;
        bool nok = false;
        const int ngy = gy + 16;
        if (k < 7) {
            nok = xok && ((unsigned)ngy < (unsigned)HH);
            if (nok) {
                int np = ngy * WW + gx;
                nfx = *(const float4*)(fxp + np);
                nfy = *(const float4*)(fyp + np);
                nd  = *(const float4*)(dp + np);
            }
        }
        if (ok) {
            const float gyf = (float)gy;
            PROC(cfx.x, cfy.x, cd.x, gx)
            PROC(cfx.y, cfy.y, cd.y, gx + 1)
            PROC(cfx.z, cfy.z, cd.z, gx + 2)
            PROC(cfx.w, cfy.w, cd.w, gx + 3)
        }
        ok = nok; gy = ngy; cfx = nfx; cfy = nfy; cd = nd;
    }
    __syncthreads();

    // writeback: 2x2 box of S per output cell, merge prepass acc if dirty,
    // divide, store out planes + count plane. merge flag is block-uniform.
    bool merge = true;
    if (flags) merge = (flags[(size_t)b * NTILE + tile] != 0);

    const float* a0 = acc + (size_t)b * HWc;
    const float* a1 = acc + (size_t)Ntot + (size_t)b * HWc;
    float*       a2 = acc + (size_t)2 * Ntot + (size_t)b * HWc;
    float* o0 = out + (size_t)b * 2 * HWc;
    float* o1 = o0 + HWc;
#pragma unroll
    for (int k = 0; k < 2; ++k) {              // 1024 float4 groups / 512 threads
        int j   = k * 512 + tid;
        int row = j >> 4;                      // core row 0..63
        int gy2 = Y0 + row;
        if (gy2 < HH) {
            int c0 = (j & 15) << 2;            // core col of lane .x
            int q  = gy2 * WW + X0 + c0;
            // S indices: output (row, c0+i) reads S rows row,row+1? no:
            // out(cy,cx): r = cy-(Y0-1) = row+1, c = cx-(X0-1) = c0+1+i.
            const int rA = (row + 1) * SSTR + c0;   // S[row+1][c0 ..]
            const int rB = row * SSTR + c0;         // S[row  ][c0 ..]
            float4 vx, vy, wv;
            {
                float a_0 = sm[rA], a_1 = sm[rA+1], a_2 = sm[rA+2], a_3 = sm[rA+3], a_4 = sm[rA+4];
                float b_0 = sm[rB], b_1 = sm[rB+1], b_2 = sm[rB+2], b_3 = sm[rB+3], b_4 = sm[rB+4];
                vx.x = a_0+a_1+b_0+b_1; vx.y = a_1+a_2+b_1+b_2;
                vx.z = a_2+a_3+b_2+b_3; vx.w = a_3+a_4+b_3+b_4;
            }
            {
                const int oA = rA + PL, oB = rB + PL;
                float a_0 = sm[oA], a_1 = sm[oA+1], a_2 = sm[oA+2], a_3 = sm[oA+3], a_4 = sm[oA+4];
                float b_0 = sm[oB], b_1 = sm[oB+1], b_2 = sm[oB+2], b_3 = sm[oB+3], b_4 = sm[oB+4];
                vy.x = a_0+a_1+b_0+b_1; vy.y = a_1+a_2+b_1+b_2;
                vy.z = a_2+a_3+b_2+b_3; vy.w = a_3+a_4+b_3+b_4;
            }
            {
                const int oA = rA + 2 * PL, oB = rB + 2 * PL;
                float a_0 = sm[oA], a_1 = sm[oA+1], a_2 = sm[oA+2], a_3 = sm[oA+3], a_4 = sm[oA+4];
                float b_0 = sm[oB], b_1 = sm[oB+1], b_2 = sm[oB+2], b_3 = sm[oB+3], b_4 = sm[oB+4];
                wv.x = a_0+a_1+b_0+b_1; wv.y = a_1+a_2+b_1+b_2;
                wv.z = a_2+a_3+b_2+b_3; wv.w = a_3+a_4+b_3+b_4;
            }
            if (merge) {
                float4 e0 = *(const float4*)(a0 + q);
                float4 e1 = *(const float4*)(a1 + q);
                float4 e2 = *(const float4*)(a2 + q);
                vx.x += e0.x; vx.y += e0.y; vx.z += e0.z; vx.w += e0.w;
                vy.x += e1.x; vy.y += e1.y; vy.z += e1.z; vy.w += e1.w;
                wv.x += e2.x; wv.y += e2.y; wv.z += e2.z; wv.w += e2.w;
            }
            float i0 = wv.x > 0.f ? 1.f / wv.x : 0.f;
            float i1 = wv.y > 0.f ? 1.f / wv.y : 0.f;
            float i2 = wv.z > 0.f ? 1.f / wv.z : 0.f;
            float i3 = wv.w > 0.f ? 1.f / wv.w : 0.f;
            float4 r0, r1;
            r0.x = vx.x * i0; r0.y = vx.y * i1; r0.z = vx.z * i2; r0.w = vx.w * i3;
            r1.x = vy.x * i0; r1.y = vy.y * i1; r1.z = vy.z * i2; r1.w = vy.w * i3;
            *(float4*)(o0 + q) = r0;
            *(float4*)(o1 + q) = r1;
            *(float4*)(a2 + q) = wv;   // final count for fill_k
        }
    }
}

// ---------------------------------------------------------------------------
// Hole fill: for count==0 pixels, average nearest filled pixel in each of the
// 4 axis directions. float4 count scan with whole-group early-out.
// ---------------------------------------------------------------------------
__global__ __launch_bounds__(256) void fill_k(float* __restrict__ out,
                                              const float* __restrict__ cw) {
    constexpr int NG = Ntot / 4;
    int g = blockIdx.x * 256 + threadIdx.x;
    if (g >= NG) return;
    float4 c4 = *(const float4*)(cw + ((size_t)g << 2));
    if (c4.x > 0.f && c4.y > 0.f && c4.z > 0.f && c4.w > 0.f) return;

    int idx0 = g << 2;
    int b = idx0 / HWc;
    int p0 = idx0 - b * HWc;
    int y = p0 / WW;
    int x0 = p0 - y * WW;

    const float* cb = cw + (size_t)b * HWc;
    const float* o0 = out + (size_t)b * 2 * HWc;
    const float* o1 = o0 + HWc;
    const float cs[4] = {c4.x, c4.y, c4.z, c4.w};

#pragma unroll
    for (int c = 0; c < 4; ++c) {
        if (cs[c] > 0.f) continue;
        int x = x0 + c;
        int p = p0 + c;
        float s = 0.f, s0 = 0.f, s1 = 0.f;
        for (int j = x - 1; j >= 0; --j) {
            int q = y * WW + j;
            if (cb[q] > 0.f) { s += 1.f; s0 += o0[q]; s1 += o1[q]; break; }
        }
        for (int j = x + 1; j < WW; ++j) {
            int q = y * WW + j;
            if (cb[q] > 0.f) { s += 1.f; s0 += o0[q]; s1 += o1[q]; break; }
        }
        for (int i = y - 1; i >= 0; --i) {
            int q = i * WW + x;
            if (cb[q] > 0.f) { s += 1.f; s0 += o0[q]; s1 += o1[q]; break; }
        }
        for (int i = y + 1; i < HH; ++i) {
            int q = i * WW + x;
            if (cb[q] > 0.f) { s += 1.f; s0 += o0[q]; s1 += o1[q]; break; }
        }
        if (s > 0.f) {
            ((float*)o0)[p] = s0 / s;
            ((float*)o1)[p] = s1 / s;
        }
    }
}

extern "C" void kernel_launch(void* const* d_in, const int* in_sizes, int n_in,
                              void* d_out, int out_size, void* d_ws, size_t ws_size,
                              hipStream_t stream) {
    const float* flow  = (const float*)d_in[0];   // (B,2,H,W)
    const float* depth = (const float*)d_in[1];   // (B,1,H,W)
    float* out = (float*)d_out;                   // (B,2,H,W)
    float* acc = (float*)d_ws;                    // 3 planes x Ntot floats = 199 MB

    const size_t accBytes  = (size_t)3 * Ntot * sizeof(float);
    const size_t flagBytes = (size_t)NTILE * BB * sizeof(int);
    int* flags = nullptr;
    if (ws_size >= accBytes + flagBytes)
        flags = (int*)((char*)d_ws + accBytes);

    const int threads = 256;

    // zero the accumulator (+ flags if present) — graph-capture-safe
    hipMemsetAsync(acc, 0, accBytes, stream);
    if (flags) hipMemsetAsync(flags, 0, flagBytes, stream);

    // rare far-flung corners via global atomics (must precede tile_k)
    prepass_k<<<(Ntot / 4 + threads - 1) / threads, threads, 0, stream>>>(
        flow, depth, acc, flags);

    // single launch: exclusive output tiles, single-anchor splat + box filter
    tile_k<<<NTILE * BB, 512, 0, stream>>>(flow, depth, acc, out, flags);

    fill_k<<<(Ntot / 4 + threads - 1) / threads, threads, 0, stream>>>(
        out, acc + (size_t)2 * Ntot);
}

// Round 4
// 637.830 us; speedup vs baseline: 2.1890x; 1.0827x over previous
//
#include <hip/hip_runtime.h>

// Problem constants (B, H, W) from the reference.
#define BB 8
#define HH 1080
#define WW 1920
constexpr int HWc  = HH * WW;          // 2,073,600
constexpr int Ntot = BB * HWc;         // 16,588,800

constexpr int TILE = 64;               // OUTPUT core side (exclusive per block)
constexpr int MAR  = 32;               // gather margin: P(|N(0,10)| > 32) ~ 7e-4 per tail
constexpr int REG  = TILE + 2 * MAR;   // 128 -> source window 128x128
constexpr int WT   = WW / TILE;        // 30 (exact)
constexpr int HT   = (HH + TILE - 1) / TILE;  // 17 (last core partial: rows 1024..1079)
constexpr int NTILE = WT * HT;         // 510 tiles per image
constexpr int GT    = NTILE * BB;      // 4080 tiles total
constexpr int CAP   = 256;             // spill records per tile (expected ~5; Poisson tail ~0)

// S-plane: corner-anchor accumulator. S[r][c] = sum of v over sources whose
// top-left corner (iyT,ixL) = (Y0-1+r, X0-1+c). Output cell = 2x2 box of S.
// Measured (R1->R3): tile_k time ~= 55us floor + atomic_lane_ops * 2.75cyc/CU;
// 3 lane-ops/source is within ~25% of the structural LDS-atomic floor.
constexpr int SDIM = 65;               // rows/cols Y0-1 .. Y0+63
constexpr int SSTR = 66;               // stride (row step shifts banks by 2)
constexpr int PL   = SSTR * SSTR;      // 4356 floats per channel plane
// LDS: 3 * 4356 * 4 = 52,272 B -> 3 blocks/CU (24 waves/CU)

static_assert(TILE == 64, "ownership test uses >>6");
static_assert((WW & 3) == 0 && (HWc & 3) == 0, "float4 groups must not straddle");
static_assert(3 * PL * 4 <= 53000, "need 3 blocks/CU");

// Workspace layout (33.3 MB total; ws proven >= 199 MB in earlier rounds):
//   [0)            cnt:     GT u32 spill counters (16,320 B; only memset)
//   [16384)        buckets: GT * CAP * float4 records {cell_bits, vx, vy, w} (16.7 MB)
//   [16384+GT*CAP*16) mask: Ntot bytes, 1 = pixel has weight (16.6 MB)

// ---------------------------------------------------------------------------
// Pre-pass: the RARE corners whose SOURCE lies outside the gather window of
// the corner's OWNER tile (|flow| beyond margin). Appends compact records to
// the owner tile's bucket; tile_k merges them during its exclusive writeback.
// Fast path: if max|fx|,|fy| over the 4-pixel group <= 30, every corner is
// provably in-window (|corner - x| <= |f|+1 <= 31 < MAR) -> exit.
// ---------------------------------------------------------------------------
__global__ __launch_bounds__(256) void prepass_k(const float* __restrict__ flow,
                                                 const float* __restrict__ depth,
                                                 unsigned* __restrict__ cnt,
                                                 float4* __restrict__ buckets) {
    constexpr int NG = Ntot / 4;
    int g = blockIdx.x * 256 + threadIdx.x;
    if (g >= NG) return;
    int idx = g << 2;
    int b = idx / HWc;
    int p = idx - b * HWc;          // multiple of 4; rows aligned (WW%4==0)
    int y = p / WW;
    int x = p - y * WW;

    const size_t fbase = (size_t)b * 2 * HWc;
    float4 fx4 = *(const float4*)(flow + fbase + p);
    float4 fy4 = *(const float4*)(flow + fbase + HWc + p);

    float m = fmaxf(fmaxf(fmaxf(fabsf(fx4.x), fabsf(fx4.y)),
                          fmaxf(fabsf(fx4.z), fabsf(fx4.w))),
                    fmaxf(fmaxf(fabsf(fy4.x), fabsf(fy4.y)),
                          fmaxf(fabsf(fy4.z), fabsf(fy4.w))));
    if (m <= 30.f) return;          // ~98% of lanes exit here

    const float fxs[4] = {fx4.x, fx4.y, fx4.z, fx4.w};
    const float fys[4] = {fy4.x, fy4.y, fy4.z, fy4.w};

#pragma unroll
    for (int c = 0; c < 4; ++c) {
        float fx = fxs[c], fy = fys[c];
        int xs = x + c;
        float x2 = (float)xs + fx;
        float y2 = (float)y + fy;
        if (!(x2 >= 0.f && x2 <= (float)(WW - 1) && y2 >= 0.f && y2 <= (float)(HH - 1)))
            continue;
        int ixL = (int)floorf(x2);          // in [0,WW-1]: validity bounds it
        int iyT = (int)floorf(y2);
        int ixR = min(ixL + 1, WW - 1);
        int iyB = min(iyT + 1, HH - 1);
        int cxs[2] = {ixL, ixR};
        int cys[2] = {iyT, iyB};
        bool anyOut = false;
#pragma unroll
        for (int a = 0; a < 2; ++a)
#pragma unroll
            for (int cc = 0; cc < 2; ++cc) {
                int cx = cxs[cc], cy = cys[a];
                int ox = (cx >> 6) * TILE - MAR;
                int oy = (cy >> 6) * TILE - MAR;
                if (!(xs >= ox && xs < ox + REG && y >= oy && y < oy + REG))
                    anyOut = true;
            }
        if (!anyOut) continue;

        float w = depth[(size_t)b * HWc + p + c];
        float vx = -fx * w;
        float vy = -fy * w;
#pragma unroll
        for (int a = 0; a < 2; ++a)
#pragma unroll
            for (int cc = 0; cc < 2; ++cc) {
                int cx = cxs[cc], cy = cys[a];
                int ox = (cx >> 6) * TILE - MAR;
                int oy = (cy >> 6) * TILE - MAR;
                if (!(xs >= ox && xs < ox + REG && y >= oy && y < oy + REG)) {
                    // append record to owner tile's bucket
                    int gtile = b * NTILE + (cy >> 6) * WT + (cx >> 6);
                    unsigned slot = atomicAdd(&cnt[gtile], 1u);
                    if (slot < (unsigned)CAP) {
                        float4 rec;
                        rec.x = __int_as_float(((cy & 63) << 6) | (cx & 63));
                        rec.y = vx; rec.z = vy; rec.w = w;
                        buckets[(size_t)gtile * CAP + slot] = rec;
                    }
                }
            }
    }
}

// ---------------------------------------------------------------------------
// Gather-tile kernel: one block (512 threads) per EXCLUSIVE 64x64 output core.
// Reads the 128x128 source window (float4 + 1-deep prefetch), splats each
// valid source ONCE (3 LDS atomics) into the S-plane at its top-left corner
// anchor (iyT,ixL) — clamp-duplicates handled by scaling x2 per clamped axis —
// then reconstructs each output cell as the 2x2 box sum of S during the
// race-free writeback: merge this tile's spill records (usually none),
// divide, store out planes + byte mask.
// ---------------------------------------------------------------------------
#define PROC(FXC, FYC, DWC, CGX)                                               \
    {                                                                          \
        float fx = (FXC), fy = (FYC);                                          \
        float x2 = (float)(CGX) + fx, y2 = gyf + fy;                           \
        if (x2 >= 0.f && x2 <= (float)(WW - 1) &&                              \
            y2 >= 0.f && y2 <= (float)(HH - 1)) {                              \
            int ixL = (int)floorf(x2);   /* validity bounds to [0,WW-1] */     \
            int iyT = (int)floorf(y2);                                         \
            unsigned cI = (unsigned)(ixL - (X0 - 1));                          \
            unsigned rI = (unsigned)(iyT - (Y0 - 1));                          \
            if (cI < (unsigned)SDIM && rI < (unsigned)SDIM) {                  \
                float w = (DWC);                                               \
                if (ixL == WW - 1) w += w;   /* duplicate corner: x clamp */   \
                if (iyT == HH - 1) w += w;   /* duplicate corner: y clamp */   \
                int cell = (int)(rI * SSTR + cI);                              \
                atomicAdd(&sm[cell],          -fx * w);                        \
                atomicAdd(&sm[cell + PL],     -fy * w);                        \
                atomicAdd(&sm[cell + 2 * PL], w);                              \
            }                                                                  \
        }                                                                      \
    }

__global__ __launch_bounds__(512, 6) void tile_k(const float* __restrict__ flow,
                                                 const float* __restrict__ depth,
                                                 const unsigned* __restrict__ cnt,
                                                 const float4* __restrict__ buckets,
                                                 float* __restrict__ out,
                                                 unsigned char* __restrict__ mask) {
    __shared__ float sm[3 * PL];       // 52.3 KB
    const int bid  = blockIdx.x;
    const int b    = bid & 7;          // image round-robin (XCD affinity heuristic)
    const int tile = bid >> 3;
    const int ty   = tile / WT;
    const int tx   = tile - ty * WT;
    const int X0 = tx * TILE, Y0 = ty * TILE;
    const int rx0 = X0 - MAR, ry0 = Y0 - MAR;
    const int tid = threadIdx.x;

    // zero LDS: 3267 float4 / 512 threads
    float4* sm4 = (float4*)sm;
    for (int i = tid; i < 3 * PL / 4; i += 512)
        sm4[i] = make_float4(0.f, 0.f, 0.f, 0.f);
    __syncthreads();

    const float* fxp = flow + (size_t)b * 2 * HWc;
    const float* fyp = fxp + HWc;
    const float* dp  = depth + (size_t)b * HWc;

    // splat: 8 iterations; each thread owns a fixed 4-pixel column group and
    // walks 16 rows/iter. float4 loads; 1-deep register prefetch pipeline.
    const int gx  = rx0 + ((tid & 31) << 2);       // group start (4-aligned)
    const bool xok = (unsigned)gx < (unsigned)WW;  // groups fully in/out in x
    int gy = ry0 + (tid >> 5);
    float4 cfx, cfy, cd;
    bool ok = xok && ((unsigned)gy < (unsigned)HH);
    if (ok) {
        int p = gy * WW + gx;
        cfx = *(const float4*)(fxp + p);
        cfy = *(const float4*)(fyp + p);
        cd  = *(const float4*)(dp + p);
    }
#pragma unroll
    for (int k = 0; k < 8; ++k) {
        float4 nfx, nfy, nd;
        bool nok = false;
        const int ngy = gy + 16;
        if (k < 7) {
            nok = xok && ((unsigned)ngy < (unsigned)HH);
            if (nok) {
                int np = ngy * WW + gx;
                nfx = *(const float4*)(fxp + np);
                nfy = *(const float4*)(fyp + np);
                nd  = *(const float4*)(dp + np);
            }
        }
        if (ok) {
            const float gyf = (float)gy;
            PROC(cfx.x, cfy.x, cd.x, gx)
            PROC(cfx.y, cfy.y, cd.y, gx + 1)
            PROC(cfx.z, cfy.z, cd.z, gx + 2)
            PROC(cfx.w, cfy.w, cd.w, gx + 3)
        }
        ok = nok; gy = ngy; cfx = nfx; cfy = nfy; cd = nd;
    }
    __syncthreads();

    // writeback: 2x2 box of S per output cell, merge spill records (rare),
    // divide, store out planes + byte mask. Zero global reads when no spills.
    const int gtile = b * NTILE + tile;
    unsigned nrec = cnt[gtile];
    if (nrec > (unsigned)CAP) nrec = CAP;
    const float4* bkt = buckets + (size_t)gtile * CAP;

    float* o0 = out + (size_t)b * 2 * HWc;
    float* o1 = o0 + HWc;
    unsigned char* mb = mask + (size_t)b * HWc;
#pragma unroll
    for (int k = 0; k < 2; ++k) {              // 1024 float4 groups / 512 threads
        int j   = k * 512 + tid;               // cell group: cells 4j..4j+3
        int row = j >> 4;                      // core row 0..63
        int gy2 = Y0 + row;
        if (gy2 < HH) {
            int c0 = (j & 15) << 2;            // core col of lane .x
            int q  = gy2 * WW + X0 + c0;
            // out(cy,cx): S row = cy-(Y0-1), col = cx-(X0-1); box of 2x2.
            const int rA = (row + 1) * SSTR + c0;   // S[row+1][c0 ..]
            const int rB = row * SSTR + c0;         // S[row  ][c0 ..]
            float4 vx, vy, wv;
            {
                float a_0 = sm[rA], a_1 = sm[rA+1], a_2 = sm[rA+2], a_3 = sm[rA+3], a_4 = sm[rA+4];
                float b_0 = sm[rB], b_1 = sm[rB+1], b_2 = sm[rB+2], b_3 = sm[rB+3], b_4 = sm[rB+4];
                vx.x = a_0+a_1+b_0+b_1; vx.y = a_1+a_2+b_1+b_2;
                vx.z = a_2+a_3+b_2+b_3; vx.w = a_3+a_4+b_3+b_4;
            }
            {
                const int oA = rA + PL, oB = rB + PL;
                float a_0 = sm[oA], a_1 = sm[oA+1], a_2 = sm[oA+2], a_3 = sm[oA+3], a_4 = sm[oA+4];
                float b_0 = sm[oB], b_1 = sm[oB+1], b_2 = sm[oB+2], b_3 = sm[oB+3], b_4 = sm[oB+4];
                vy.x = a_0+a_1+b_0+b_1; vy.y = a_1+a_2+b_1+b_2;
                vy.z = a_2+a_3+b_2+b_3; vy.w = a_3+a_4+b_3+b_4;
            }
            {
                const int oA = rA + 2 * PL, oB = rB + 2 * PL;
                float a_0 = sm[oA], a_1 = sm[oA+1], a_2 = sm[oA+2], a_3 = sm[oA+3], a_4 = sm[oA+4];
                float b_0 = sm[oB], b_1 = sm[oB+1], b_2 = sm[oB+2], b_3 = sm[oB+3], b_4 = sm[oB+4];
                wv.x = a_0+a_1+b_0+b_1; wv.y = a_1+a_2+b_1+b_2;
                wv.z = a_2+a_3+b_2+b_3; wv.w = a_3+a_4+b_3+b_4;
            }
            // merge spill records (block-uniform loop; nrec==0 for ~99.9% tiles)
            for (unsigned r = 0; r < nrec; ++r) {
                float4 rec = bkt[r];
                int cc = __float_as_int(rec.x);
                if ((cc >> 2) == j) {
                    switch (cc & 3) {
                    case 0: vx.x += rec.y; vy.x += rec.z; wv.x += rec.w; break;
                    case 1: vx.y += rec.y; vy.y += rec.z; wv.y += rec.w; break;
                    case 2: vx.z += rec.y; vy.z += rec.z; wv.z += rec.w; break;
                    default: vx.w += rec.y; vy.w += rec.z; wv.w += rec.w; break;
                    }
                }
            }
            float i0 = wv.x > 0.f ? 1.f / wv.x : 0.f;
            float i1 = wv.y > 0.f ? 1.f / wv.y : 0.f;
            float i2 = wv.z > 0.f ? 1.f / wv.z : 0.f;
            float i3 = wv.w > 0.f ? 1.f / wv.w : 0.f;
            float4 r0, r1;
            r0.x = vx.x * i0; r0.y = vx.y * i1; r0.z = vx.z * i2; r0.w = vx.w * i3;
            r1.x = vy.x * i0; r1.y = vy.y * i1; r1.z = vy.z * i2; r1.w = vy.w * i3;
            *(float4*)(o0 + q) = r0;
            *(float4*)(o1 + q) = r1;
            uchar4 mk;
            mk.x = (unsigned char)(wv.x > 0.f);
            mk.y = (unsigned char)(wv.y > 0.f);
            mk.z = (unsigned char)(wv.z > 0.f);
            mk.w = (unsigned char)(wv.w > 0.f);
            *(uchar4*)(mb + q) = mk;           // q % 4 == 0 by construction
        }
    }
}

// ---------------------------------------------------------------------------
// Hole fill: for mask==0 pixels, average nearest filled pixel in each of the
// 4 axis directions. Byte-mask scans (dense cache lines), float4 group
// early-out, value loads only on hit.
// ---------------------------------------------------------------------------
__global__ __launch_bounds__(256) void fill_k(float* __restrict__ out,
                                              const unsigned char* __restrict__ mask) {
    constexpr int NG = Ntot / 4;
    int g = blockIdx.x * 256 + threadIdx.x;
    if (g >= NG) return;
    int idx0 = g << 2;
    uchar4 m4 = *(const uchar4*)(mask + idx0);
    if (m4.x & m4.y & m4.z & m4.w) return;     // all 4 pixels filled

    int b = idx0 / HWc;
    int p0 = idx0 - b * HWc;
    int y = p0 / WW;
    int x0 = p0 - y * WW;

    const unsigned char* mb = mask + (size_t)b * HWc;
    const float* o0 = out + (size_t)b * 2 * HWc;
    const float* o1 = o0 + HWc;
    const unsigned char ms[4] = {m4.x, m4.y, m4.z, m4.w};

#pragma unroll
    for (int c = 0; c < 4; ++c) {
        if (ms[c]) continue;
        int x = x0 + c;
        int p = p0 + c;
        float s = 0.f, s0 = 0.f, s1 = 0.f;
        for (int j = x - 1; j >= 0; --j) {
            if (mb[y * WW + j]) { int q = y * WW + j; s += 1.f; s0 += o0[q]; s1 += o1[q]; break; }
        }
        for (int j = x + 1; j < WW; ++j) {
            if (mb[y * WW + j]) { int q = y * WW + j; s += 1.f; s0 += o0[q]; s1 += o1[q]; break; }
        }
        for (int i = y - 1; i >= 0; --i) {
            if (mb[i * WW + x]) { int q = i * WW + x; s += 1.f; s0 += o0[q]; s1 += o1[q]; break; }
        }
        for (int i = y + 1; i < HH; ++i) {
            if (mb[i * WW + x]) { int q = i * WW + x; s += 1.f; s0 += o0[q]; s1 += o1[q]; break; }
        }
        if (s > 0.f) {
            ((float*)o0)[p] = s0 / s;
            ((float*)o1)[p] = s1 / s;
        }
    }
}

extern "C" void kernel_launch(void* const* d_in, const int* in_sizes, int n_in,
                              void* d_out, int out_size, void* d_ws, size_t ws_size,
                              hipStream_t stream) {
    const float* flow  = (const float*)d_in[0];   // (B,2,H,W)
    const float* depth = (const float*)d_in[1];   // (B,1,H,W)
    float* out = (float*)d_out;                   // (B,2,H,W)

    unsigned char* wsb = (unsigned char*)d_ws;
    unsigned* cnt      = (unsigned*)wsb;                       // 16,320 B
    float4*  buckets   = (float4*)(wsb + 16384);               // 16.7 MB
    unsigned char* mask = wsb + 16384 + (size_t)GT * CAP * 16; // 16.6 MB
    // total ~33.3 MB (ws proven >= 199 MB in earlier rounds)

    const int threads = 256;

    // only remaining memset: 16 KB of spill counters
    hipMemsetAsync(cnt, 0, (size_t)GT * sizeof(unsigned), stream);

    // rare far-flung corners -> compact per-tile records (must precede tile_k)
    prepass_k<<<(Ntot / 4 + threads - 1) / threads, threads, 0, stream>>>(
        flow, depth, cnt, buckets);

    // single launch: exclusive output tiles, single-anchor splat + box filter
    tile_k<<<GT, 512, 0, stream>>>(flow, depth, cnt, buckets, out, mask);

    fill_k<<<(Ntot / 4 + threads - 1) / threads, threads, 0, stream>>>(out, mask);
}

// Round 6
// 606.945 us; speedup vs baseline: 2.3004x; 1.0509x over previous
//
#include <hip/hip_runtime.h>

// Problem constants (B, H, W) from the reference.
#define BB 8
#define HH 1080
#define WW 1920
constexpr int HWc  = HH * WW;          // 2,073,600
constexpr int Ntot = BB * HWc;         // 16,588,800

constexpr int TILE = 64;               // OUTPUT core side (exclusive per block)
constexpr int MAR  = 32;               // gather margin: P(|N(0,10)| > 32) ~ 7e-4 per tail
constexpr int REG  = TILE + 2 * MAR;   // 128 -> source window 128x128
constexpr int WT   = WW / TILE;        // 30 (exact)
constexpr int HT   = (HH + TILE - 1) / TILE;  // 17 (last core partial: rows 1024..1079)
constexpr int NTILE = WT * HT;         // 510 tiles per image
constexpr int GT    = NTILE * BB;      // 4080 tiles total
constexpr int CAP   = 256;             // spill records per tile (avg ~60 when present)

// S-plane: corner-anchor accumulator. S[r][c] = sum of v over sources whose
// top-left corner (iyT,ixL) = (Y0-1+r, X0-1+c). Output cell = 2x2 box of S.
constexpr int SDIM = 65;               // rows/cols Y0-1 .. Y0+63
constexpr int SSTR = 66;               // stride (row step shifts banks by 2)
constexpr int PL   = SSTR * SSTR;      // 4356 floats per channel plane

static_assert(TILE == 64, "ownership test uses >>6");
static_assert((WW & 3) == 0 && (HWc & 3) == 0, "float4 groups must not straddle");
static_assert(3 * PL * 4 <= 53000, "need 3 blocks/CU");

// Workspace layout (~100 MB; ws proven >= 199 MB in earlier rounds):
//   [0)        cnt:     GT u32 spill counters (16,320 B; only memset)
//   [16384)    buckets: GT * CAP * float4 {cell_bits, vx, vy, w}   (16.7 MB)
//   [+]        mask:    Ntot bytes, 1 = pixel has weight           (16.6 MB)
//   [+]        wplane:  Ntot floats, final per-pixel weight sum    (66.4 MB)
constexpr size_t OFF_BKT  = 16384;
constexpr size_t OFF_MASK = OFF_BKT + (size_t)GT * CAP * 16;
constexpr size_t OFF_W    = OFF_MASK + (size_t)Ntot;   // 16-aligned (checked)
static_assert(OFF_W % 16 == 0, "wplane must be float4-aligned");

// ---------------------------------------------------------------------------
// Spill append (rare): a corner whose owner tile's 128x128 window does NOT
// contain the source. Bit-identical predicate to the old prepass. Duplicate
// (clamped) corners produce duplicate records == reference's double-add.
// Gate soundness: called only when |fx|>30 or |fy|>30; if both <=30 every
// corner is within 31 px of the source and the owner window margin is 32.
// ---------------------------------------------------------------------------
__device__ inline void spill_append(int b, int xs, int ys, int ixL, int iyT,
                                    float fx, float fy, float w,
                                    unsigned* cnt, float4* buckets) {
    int ixR = min(ixL + 1, WW - 1);
    int iyB = min(iyT + 1, HH - 1);
    int cxs[2] = {ixL, ixR};
    int cys[2] = {iyT, iyB};
    float vx = -fx * w, vy = -fy * w;
#pragma unroll
    for (int a = 0; a < 2; ++a)
#pragma unroll
        for (int cc = 0; cc < 2; ++cc) {
            int cx = cxs[cc], cy = cys[a];
            int ox = (cx >> 6) * TILE - MAR;
            int oy = (cy >> 6) * TILE - MAR;
            if (!(xs >= ox && xs < ox + REG && ys >= oy && ys < oy + REG)) {
                int gtile = b * NTILE + (cy >> 6) * WT + (cx >> 6);
                unsigned slot = atomicAdd(&cnt[gtile], 1u);
                if (slot < (unsigned)CAP) {
                    float4 rec;
                    rec.x = __int_as_float(((cy & 63) << 6) | (cx & 63));
                    rec.y = vx; rec.z = vy; rec.w = w;
                    buckets[(size_t)gtile * CAP + slot] = rec;
                }
            }
        }
}

// ---------------------------------------------------------------------------
// Gather-tile kernel: one block (512 threads) per EXCLUSIVE 64x64 output core.
// Reads the 128x128 source window (float4 + 1-deep prefetch), splats each
// valid source ONCE (3 LDS atomics) into the S-plane at its top-left corner
// anchor — clamp-duplicates handled by scaling x2 per clamped axis — and, for
// CORE pixels with |f|>30 (rare), appends out-of-window corner records to the
// owner tile's bucket (consumed later by fixup_k). Writeback reconstructs each
// output cell as the 2x2 box sum of S: divide, store out planes + w-plane +
// byte mask. No prepass, no global accumulator.
// ---------------------------------------------------------------------------
#define PROC(FXC, FYC, DWC, CGX)                                               \
    {                                                                          \
        float fx = (FXC), fy = (FYC);                                          \
        float x2 = (float)(CGX) + fx, y2 = gyf + fy;                           \
        if (x2 >= 0.f && x2 <= (float)(WW - 1) &&                              \
            y2 >= 0.f && y2 <= (float)(HH - 1)) {                              \
            int ixL = (int)floorf(x2);   /* validity bounds to [0,WW-1] */     \
            int iyT = (int)floorf(y2);                                         \
            unsigned cI = (unsigned)(ixL - (X0 - 1));                          \
            unsigned rI = (unsigned)(iyT - (Y0 - 1));                          \
            if (cI < (unsigned)SDIM && rI < (unsigned)SDIM) {                  \
                float w = (DWC);                                               \
                if (ixL == WW - 1) w += w;   /* duplicate corner: x clamp */   \
                if (iyT == HH - 1) w += w;   /* duplicate corner: y clamp */   \
                int cell = (int)(rI * SSTR + cI);                              \
                atomicAdd(&sm[cell],          -fx * w);                        \
                atomicAdd(&sm[cell + PL],     -fy * w);                        \
                atomicAdd(&sm[cell + 2 * PL], w);                              \
            }                                                                  \
            if (core && (fabsf(fx) > 30.f || fabsf(fy) > 30.f))                \
                spill_append(b, (CGX), gy, ixL, iyT, fx, fy, (DWC),            \
                             cnt, buckets);                                    \
        }                                                                      \
    }

__global__ __launch_bounds__(512, 6) void tile_k(const float* __restrict__ flow,
                                                 const float* __restrict__ depth,
                                                 unsigned* __restrict__ cnt,
                                                 float4* __restrict__ buckets,
                                                 float* __restrict__ out,
                                                 unsigned char* __restrict__ mask,
                                                 float* __restrict__ wplane) {
    __shared__ float sm[3 * PL];       // 52.3 KB
    const int bid  = blockIdx.x;
    const int b    = bid & 7;          // image round-robin (XCD affinity heuristic)
    const int tile = bid >> 3;
    const int ty   = tile / WT;
    const int tx   = tile - ty * WT;
    const int X0 = tx * TILE, Y0 = ty * TILE;
    const int rx0 = X0 - MAR, ry0 = Y0 - MAR;
    const int tid = threadIdx.x;

    // zero LDS: 3267 float4 / 512 threads
    float4* sm4 = (float4*)sm;
    for (int i = tid; i < 3 * PL / 4; i += 512)
        sm4[i] = make_float4(0.f, 0.f, 0.f, 0.f);
    __syncthreads();

    const float* fxp = flow + (size_t)b * 2 * HWc;
    const float* fyp = fxp + HWc;
    const float* dp  = depth + (size_t)b * HWc;

    // splat: 8 iterations; each thread owns a fixed 4-pixel column group and
    // walks 16 rows/iter. float4 loads; 1-deep register prefetch pipeline.
    const int gx  = rx0 + ((tid & 31) << 2);       // group start (4-aligned)
    const bool xok = (unsigned)gx < (unsigned)WW;  // groups fully in/out in x
    // core-x is group-uniform: gx 4-aligned, X0 64-aligned -> no straddle
    const bool xin = (unsigned)(gx - X0) < (unsigned)TILE;
    int gy = ry0 + (tid >> 5);
    float4 cfx, cfy, cd;
    bool ok = xok && ((unsigned)gy < (unsigned)HH);
    if (ok) {
        int p = gy * WW + gx;
        cfx = *(const float4*)(fxp + p);
        cfy = *(const float4*)(fyp + p);
        cd  = *(const float4*)(dp + p);
    }
#pragma unroll
    for (int k = 0; k < 8; ++k) {
        float4 nfx, nfy, nd;
        bool nok = false;
        const int ngy = gy + 16;
        if (k < 7) {
            nok = xok && ((unsigned)ngy < (unsigned)HH);
            if (nok) {
                int np = ngy * WW + gx;
                nfx = *(const float4*)(fxp + np);
                nfy = *(const float4*)(fyp + np);
                nd  = *(const float4*)(dp + np);
            }
        }
        if (ok) {
            const float gyf = (float)gy;
            const bool core = xin && ((unsigned)(gy - Y0) < (unsigned)TILE);
            PROC(cfx.x, cfy.x, cd.x, gx)
            PROC(cfx.y, cfy.y, cd.y, gx + 1)
            PROC(cfx.z, cfy.z, cd.z, gx + 2)
            PROC(cfx.w, cfy.w, cd.w, gx + 3)
        }
        ok = nok; gy = ngy; cfx = nfx; cfy = nfy; cd = nd;
    }
    __syncthreads();

    // writeback: 2x2 box of S per output cell, divide, store out planes +
    // w-plane + byte mask. Exclusive — no atomics, no merge.
    float* o0 = out + (size_t)b * 2 * HWc;
    float* o1 = o0 + HWc;
    float* wp = wplane + (size_t)b * HWc;
    unsigned char* mb = mask + (size_t)b * HWc;
#pragma unroll
    for (int k = 0; k < 2; ++k) {              // 1024 float4 groups / 512 threads
        int j   = k * 512 + tid;               // cell group: cells 4j..4j+3
        int row = j >> 4;                      // core row 0..63
        int gy2 = Y0 + row;
        if (gy2 < HH) {
            int c0 = (j & 15) << 2;            // core col of lane .x
            int q  = gy2 * WW + X0 + c0;
            const int rA = (row + 1) * SSTR + c0;   // S[row+1][c0 ..]
            const int rB = row * SSTR + c0;         // S[row  ][c0 ..]
            float4 vx, vy, wv;
            {
                float a_0 = sm[rA], a_1 = sm[rA+1], a_2 = sm[rA+2], a_3 = sm[rA+3], a_4 = sm[rA+4];
                float b_0 = sm[rB], b_1 = sm[rB+1], b_2 = sm[rB+2], b_3 = sm[rB+3], b_4 = sm[rB+4];
                vx.x = a_0+a_1+b_0+b_1; vx.y = a_1+a_2+b_1+b_2;
                vx.z = a_2+a_3+b_2+b_3; vx.w = a_3+a_4+b_3+b_4;
            }
            {
                const int oA = rA + PL, oB = rB + PL;
                float a_0 = sm[oA], a_1 = sm[oA+1], a_2 = sm[oA+2], a_3 = sm[oA+3], a_4 = sm[oA+4];
                float b_0 = sm[oB], b_1 = sm[oB+1], b_2 = sm[oB+2], b_3 = sm[oB+3], b_4 = sm[oB+4];
                vy.x = a_0+a_1+b_0+b_1; vy.y = a_1+a_2+b_1+b_2;
                vy.z = a_2+a_3+b_2+b_3; vy.w = a_3+a_4+b_3+b_4;
            }
            {
                const int oA = rA + 2 * PL, oB = rB + 2 * PL;
                float a_0 = sm[oA], a_1 = sm[oA+1], a_2 = sm[oA+2], a_3 = sm[oA+3], a_4 = sm[oA+4];
                float b_0 = sm[oB], b_1 = sm[oB+1], b_2 = sm[oB+2], b_3 = sm[oB+3], b_4 = sm[oB+4];
                wv.x = a_0+a_1+b_0+b_1; wv.y = a_1+a_2+b_1+b_2;
                wv.z = a_2+a_3+b_2+b_3; wv.w = a_3+a_4+b_3+b_4;
            }
            float i0 = wv.x > 0.f ? 1.f / wv.x : 0.f;
            float i1 = wv.y > 0.f ? 1.f / wv.y : 0.f;
            float i2 = wv.z > 0.f ? 1.f / wv.z : 0.f;
            float i3 = wv.w > 0.f ? 1.f / wv.w : 0.f;
            float4 r0, r1;
            r0.x = vx.x * i0; r0.y = vx.y * i1; r0.z = vx.z * i2; r0.w = vx.w * i3;
            r1.x = vy.x * i0; r1.y = vy.y * i1; r1.z = vy.z * i2; r1.w = vy.w * i3;
            *(float4*)(o0 + q) = r0;
            *(float4*)(o1 + q) = r1;
            *(float4*)(wp + q) = wv;           // for fixup_k renormalization
            uchar4 mk;
            mk.x = (unsigned char)(wv.x > 0.f);
            mk.y = (unsigned char)(wv.y > 0.f);
            mk.z = (unsigned char)(wv.z > 0.f);
            mk.w = (unsigned char)(wv.w > 0.f);
            *(uchar4*)(mb + q) = mk;           // q % 4 == 0 by construction
        }
    }
}

// ---------------------------------------------------------------------------
// Fixup: merge spill records into the finalized output. One block per tile;
// ~99% of blocks read cnt==0 and exit (block-uniform, before any barrier).
// Active blocks combine records by cell in LDS (race-free), then renormalize
// each touched cell exactly: out_new = (out_old*w_old + sum_v)/(w_old+sum_w).
// Updates mask. Must run BEFORE fill_k (spills can fill holes).
// ---------------------------------------------------------------------------
__global__ __launch_bounds__(256) void fixup_k(const unsigned* __restrict__ cnt,
                                               const float4* __restrict__ buckets,
                                               float* __restrict__ out,
                                               const float* __restrict__ wplane,
                                               unsigned char* __restrict__ mask) {
    __shared__ float s[3 * 4096];      // 48 KB
    int gtile = blockIdx.x;
    unsigned n = cnt[gtile];
    if (n == 0) return;
    if (n > (unsigned)CAP) n = CAP;
    int b  = gtile / NTILE;
    int t  = gtile - b * NTILE;
    int ty = t / WT, tx = t - ty * WT;
    int X0 = tx * TILE, Y0 = ty * TILE;

    float4* s4 = (float4*)s;
    for (int i = threadIdx.x; i < 3 * 4096 / 4; i += 256)
        s4[i] = make_float4(0.f, 0.f, 0.f, 0.f);
    __syncthreads();

    const float4* bkt = buckets + (size_t)gtile * CAP;
    for (unsigned r = threadIdx.x; r < n; r += 256) {
        float4 rec = bkt[r];
        int cell = __float_as_int(rec.x);
        atomicAdd(&s[cell],        rec.y);
        atomicAdd(&s[cell + 4096], rec.z);
        atomicAdd(&s[cell + 8192], rec.w);
    }
    __syncthreads();

    float* o0 = out + (size_t)b * 2 * HWc;
    float* o1 = o0 + HWc;
    const float* wp = wplane + (size_t)b * HWc;
    unsigned char* mb = mask + (size_t)b * HWc;
    for (int cell = threadIdx.x; cell < 4096; cell += 256) {
        float ws = s[cell + 8192];
        if (ws != 0.f) {               // depth > 0.1 -> every record has w > 0
            int cy = Y0 + (cell >> 6), cx = X0 + (cell & 63);
            if (cy < HH) {
                int q = cy * WW + cx;
                float w0 = wp[q];
                float wn = w0 + ws;
                float v0 = o0[q] * w0 + s[cell];
                float v1 = o1[q] * w0 + s[cell + 4096];
                float inv = wn > 0.f ? 1.f / wn : 0.f;
                o0[q] = v0 * inv;
                o1[q] = v1 * inv;
                mb[q] = 1;
            }
        }
    }
}

// ---------------------------------------------------------------------------
// Hole fill: for mask==0 pixels, average nearest filled pixel in each of the
// 4 axis directions. Byte-mask scans, float4 group early-out.
// ---------------------------------------------------------------------------
__global__ __launch_bounds__(256) void fill_k(float* __restrict__ out,
                                              const unsigned char* __restrict__ mask) {
    constexpr int NG = Ntot / 4;
    int g = blockIdx.x * 256 + threadIdx.x;
    if (g >= NG) return;
    int idx0 = g << 2;
    uchar4 m4 = *(const uchar4*)(mask + idx0);
    if (m4.x & m4.y & m4.z & m4.w) return;     // all 4 pixels filled

    int b = idx0 / HWc;
    int p0 = idx0 - b * HWc;
    int y = p0 / WW;
    int x0 = p0 - y * WW;

    const unsigned char* mb = mask + (size_t)b * HWc;
    const float* o0 = out + (size_t)b * 2 * HWc;
    const float* o1 = o0 + HWc;
    const unsigned char ms[4] = {m4.x, m4.y, m4.z, m4.w};

#pragma unroll
    for (int c = 0; c < 4; ++c) {
        if (ms[c]) continue;
        int x = x0 + c;
        int p = p0 + c;
        float s = 0.f, s0 = 0.f, s1 = 0.f;
        for (int j = x - 1; j >= 0; --j) {
            if (mb[y * WW + j]) { int q = y * WW + j; s += 1.f; s0 += o0[q]; s1 += o1[q]; break; }
        }
        for (int j = x + 1; j < WW; ++j) {
            if (mb[y * WW + j]) { int q = y * WW + j; s += 1.f; s0 += o0[q]; s1 += o1[q]; break; }
        }
        for (int i = y - 1; i >= 0; --i) {
            if (mb[i * WW + x]) { int q = i * WW + x; s += 1.f; s0 += o0[q]; s1 += o1[q]; break; }
        }
        for (int i = y + 1; i < HH; ++i) {
            if (mb[i * WW + x]) { int q = i * WW + x; s += 1.f; s0 += o0[q]; s1 += o1[q]; break; }
        }
        if (s > 0.f) {
            ((float*)o0)[p] = s0 / s;
            ((float*)o1)[p] = s1 / s;
        }
    }
}

extern "C" void kernel_launch(void* const* d_in, const int* in_sizes, int n_in,
                              void* d_out, int out_size, void* d_ws, size_t ws_size,
                              hipStream_t stream) {
    const float* flow  = (const float*)d_in[0];   // (B,2,H,W)
    const float* depth = (const float*)d_in[1];   // (B,1,H,W)
    float* out = (float*)d_out;                   // (B,2,H,W)

    unsigned char* wsb = (unsigned char*)d_ws;
    unsigned* cnt       = (unsigned*)wsb;
    float4*  buckets    = (float4*)(wsb + OFF_BKT);
    unsigned char* mask = wsb + OFF_MASK;
    float*   wplane     = (float*)(wsb + OFF_W);

    const int threads = 256;

    // only memset: 16 KB of spill counters
    hipMemsetAsync(cnt, 0, (size_t)GT * sizeof(unsigned), stream);

    // fused: splat + spill discovery + average + mask/w-plane
    tile_k<<<GT, 512, 0, stream>>>(flow, depth, cnt, buckets, out, mask, wplane);

    // merge rare spill records (must precede fill_k)
    fixup_k<<<GT, threads, 0, stream>>>(cnt, buckets, out, wplane, mask);

    fill_k<<<(Ntot / 4 + threads - 1) / threads, threads, 0, stream>>>(out, mask);
}

// Round 7
// 597.288 us; speedup vs baseline: 2.3376x; 1.0162x over previous
//
#include <hip/hip_runtime.h>

// Problem constants (B, H, W) from the reference.
#define BB 8
#define HH 1080
#define WW 1920
constexpr int HWc  = HH * WW;          // 2,073,600
constexpr int Ntot = BB * HWc;         // 16,588,800

constexpr int TILE = 64;               // OUTPUT core side (exclusive per block)
constexpr int MAR  = 32;               // gather margin: P(|N(0,10)| > 32) ~ 7e-4 per tail
constexpr int REG  = TILE + 2 * MAR;   // 128 -> source window 128x128
constexpr int WT   = WW / TILE;        // 30 (exact)
constexpr int HT   = (HH + TILE - 1) / TILE;  // 17 (last core partial: rows 1024..1079)
constexpr int NTILE = WT * HT;         // 510 tiles per image
constexpr int GT    = NTILE * BB;      // 4080 tiles total
constexpr int CAP   = 256;             // spill records per tile (avg ~60 when present)

// S-plane: corner-anchor accumulator. S[r][c] = sum of v over sources whose
// top-left corner (iyT,ixL) = (Y0-1+r, X0-1+c). Output cell = 2x2 box of S.
constexpr int SDIM = 65;               // rows/cols Y0-1 .. Y0+63
constexpr int SSTR = 66;               // stride (row step shifts banks by 2)
constexpr int PL   = SSTR * SSTR;      // 4356 floats per channel plane

static_assert(TILE == 64, "ownership test uses >>6");
static_assert((WW & 3) == 0 && (HWc & 3) == 0, "float4 groups must not straddle");
static_assert(3 * PL * 4 <= 53000, "need 3 blocks/CU");

// Workspace layout (~100 MB; ws proven >= 199 MB in earlier rounds):
//   [0)        cnt:     GT u32 spill counters (16,320 B; only memset)
//   [16384)    buckets: GT * CAP * float4 {cell_bits, vx, vy, w}   (16.7 MB)
//   [+]        mask:    Ntot bytes, 1 = pixel has weight           (16.6 MB)
//   [+]        wplane:  Ntot floats, final per-pixel weight sum    (66.4 MB)
constexpr size_t OFF_BKT  = 16384;
constexpr size_t OFF_MASK = OFF_BKT + (size_t)GT * CAP * 16;
constexpr size_t OFF_W    = OFF_MASK + (size_t)Ntot;   // 16-aligned (checked)
static_assert(OFF_W % 16 == 0, "wplane must be float4-aligned");

// ---------------------------------------------------------------------------
// Spill append (rare): a corner whose owner tile's 128x128 window does NOT
// contain the source. Duplicate (clamped) corners produce duplicate records
// == reference's double-add. Gate: only called when |fx|>30 or |fy|>30.
// ---------------------------------------------------------------------------
__device__ inline void spill_append(int b, int xs, int ys, int ixL, int iyT,
                                    float fx, float fy, float w,
                                    unsigned* cnt, float4* buckets) {
    int ixR = min(ixL + 1, WW - 1);
    int iyB = min(iyT + 1, HH - 1);
    int cxs[2] = {ixL, ixR};
    int cys[2] = {iyT, iyB};
    float vx = -fx * w, vy = -fy * w;
#pragma unroll
    for (int a = 0; a < 2; ++a)
#pragma unroll
        for (int cc = 0; cc < 2; ++cc) {
            int cx = cxs[cc], cy = cys[a];
            int ox = (cx >> 6) * TILE - MAR;
            int oy = (cy >> 6) * TILE - MAR;
            if (!(xs >= ox && xs < ox + REG && ys >= oy && ys < oy + REG)) {
                int gtile = b * NTILE + (cy >> 6) * WT + (cx >> 6);
                unsigned slot = atomicAdd(&cnt[gtile], 1u);
                if (slot < (unsigned)CAP) {
                    float4 rec;
                    rec.x = __int_as_float(((cy & 63) << 6) | (cx & 63));
                    rec.y = vx; rec.z = vy; rec.w = w;
                    buckets[(size_t)gtile * CAP + slot] = rec;
                }
            }
        }
}

// ---------------------------------------------------------------------------
// Gather-tile kernel (unchanged from R6, verified): one block (512 threads)
// per EXCLUSIVE 64x64 output core. Splat-once into S-plane (3 LDS atomics /
// source), spill discovery for core |f|>30 pixels, 2x2 box-sum writeback with
// divide; stores out planes + w-plane + byte mask.
// ---------------------------------------------------------------------------
#define PROC(FXC, FYC, DWC, CGX)                                               \
    {                                                                          \
        float fx = (FXC), fy = (FYC);                                          \
        float x2 = (float)(CGX) + fx, y2 = gyf + fy;                           \
        if (x2 >= 0.f && x2 <= (float)(WW - 1) &&                              \
            y2 >= 0.f && y2 <= (float)(HH - 1)) {                              \
            int ixL = (int)floorf(x2);   /* validity bounds to [0,WW-1] */     \
            int iyT = (int)floorf(y2);                                         \
            unsigned cI = (unsigned)(ixL - (X0 - 1));                          \
            unsigned rI = (unsigned)(iyT - (Y0 - 1));                          \
            if (cI < (unsigned)SDIM && rI < (unsigned)SDIM) {                  \
                float w = (DWC);                                               \
                if (ixL == WW - 1) w += w;   /* duplicate corner: x clamp */   \
                if (iyT == HH - 1) w += w;   /* duplicate corner: y clamp */   \
                int cell = (int)(rI * SSTR + cI);                              \
                atomicAdd(&sm[cell],          -fx * w);                        \
                atomicAdd(&sm[cell + PL],     -fy * w);                        \
                atomicAdd(&sm[cell + 2 * PL], w);                              \
            }                                                                  \
            if (core && (fabsf(fx) > 30.f || fabsf(fy) > 30.f))                \
                spill_append(b, (CGX), gy, ixL, iyT, fx, fy, (DWC),            \
                             cnt, buckets);                                    \
        }                                                                      \
    }

__global__ __launch_bounds__(512, 6) void tile_k(const float* __restrict__ flow,
                                                 const float* __restrict__ depth,
                                                 unsigned* __restrict__ cnt,
                                                 float4* __restrict__ buckets,
                                                 float* __restrict__ out,
                                                 unsigned char* __restrict__ mask,
                                                 float* __restrict__ wplane) {
    __shared__ float sm[3 * PL];       // 52.3 KB
    const int bid  = blockIdx.x;
    const int b    = bid & 7;          // image round-robin (XCD affinity heuristic)
    const int tile = bid >> 3;
    const int ty   = tile / WT;
    const int tx   = tile - ty * WT;
    const int X0 = tx * TILE, Y0 = ty * TILE;
    const int rx0 = X0 - MAR, ry0 = Y0 - MAR;
    const int tid = threadIdx.x;

    // zero LDS: 3267 float4 / 512 threads
    float4* sm4 = (float4*)sm;
    for (int i = tid; i < 3 * PL / 4; i += 512)
        sm4[i] = make_float4(0.f, 0.f, 0.f, 0.f);
    __syncthreads();

    const float* fxp = flow + (size_t)b * 2 * HWc;
    const float* fyp = fxp + HWc;
    const float* dp  = depth + (size_t)b * HWc;

    // splat: 8 iterations; each thread owns a fixed 4-pixel column group and
    // walks 16 rows/iter. float4 loads; 1-deep register prefetch pipeline.
    const int gx  = rx0 + ((tid & 31) << 2);       // group start (4-aligned)
    const bool xok = (unsigned)gx < (unsigned)WW;  // groups fully in/out in x
    const bool xin = (unsigned)(gx - X0) < (unsigned)TILE;
    int gy = ry0 + (tid >> 5);
    float4 cfx, cfy, cd;
    bool ok = xok && ((unsigned)gy < (unsigned)HH);
    if (ok) {
        int p = gy * WW + gx;
        cfx = *(const float4*)(fxp + p);
        cfy = *(const float4*)(fyp + p);
        cd  = *(const float4*)(dp + p);
    }
#pragma unroll
    for (int k = 0; k < 8; ++k) {
        float4 nfx, nfy, nd;
        bool nok = false;
        const int ngy = gy + 16;
        if (k < 7) {
            nok = xok && ((unsigned)ngy < (unsigned)HH);
            if (nok) {
                int np = ngy * WW + gx;
                nfx = *(const float4*)(fxp + np);
                nfy = *(const float4*)(fyp + np);
                nd  = *(const float4*)(dp + np);
            }
        }
        if (ok) {
            const float gyf = (float)gy;
            const bool core = xin && ((unsigned)(gy - Y0) < (unsigned)TILE);
            PROC(cfx.x, cfy.x, cd.x, gx)
            PROC(cfx.y, cfy.y, cd.y, gx + 1)
            PROC(cfx.z, cfy.z, cd.z, gx + 2)
            PROC(cfx.w, cfy.w, cd.w, gx + 3)
        }
        ok = nok; gy = ngy; cfx = nfx; cfy = nfy; cd = nd;
    }
    __syncthreads();

    // writeback: 2x2 box of S per output cell, divide, store out planes +
    // w-plane + byte mask. Exclusive — no atomics, no merge.
    float* o0 = out + (size_t)b * 2 * HWc;
    float* o1 = o0 + HWc;
    float* wp = wplane + (size_t)b * HWc;
    unsigned char* mb = mask + (size_t)b * HWc;
#pragma unroll
    for (int k = 0; k < 2; ++k) {              // 1024 float4 groups / 512 threads
        int j   = k * 512 + tid;               // cell group: cells 4j..4j+3
        int row = j >> 4;                      // core row 0..63
        int gy2 = Y0 + row;
        if (gy2 < HH) {
            int c0 = (j & 15) << 2;            // core col of lane .x
            int q  = gy2 * WW + X0 + c0;
            const int rA = (row + 1) * SSTR + c0;   // S[row+1][c0 ..]
            const int rB = row * SSTR + c0;         // S[row  ][c0 ..]
            float4 vx, vy, wv;
            {
                float a_0 = sm[rA], a_1 = sm[rA+1], a_2 = sm[rA+2], a_3 = sm[rA+3], a_4 = sm[rA+4];
                float b_0 = sm[rB], b_1 = sm[rB+1], b_2 = sm[rB+2], b_3 = sm[rB+3], b_4 = sm[rB+4];
                vx.x = a_0+a_1+b_0+b_1; vx.y = a_1+a_2+b_1+b_2;
                vx.z = a_2+a_3+b_2+b_3; vx.w = a_3+a_4+b_3+b_4;
            }
            {
                const int oA = rA + PL, oB = rB + PL;
                float a_0 = sm[oA], a_1 = sm[oA+1], a_2 = sm[oA+2], a_3 = sm[oA+3], a_4 = sm[oA+4];
                float b_0 = sm[oB], b_1 = sm[oB+1], b_2 = sm[oB+2], b_3 = sm[oB+3], b_4 = sm[oB+4];
                vy.x = a_0+a_1+b_0+b_1; vy.y = a_1+a_2+b_1+b_2;
                vy.z = a_2+a_3+b_2+b_3; vy.w = a_3+a_4+b_3+b_4;
            }
            {
                const int oA = rA + 2 * PL, oB = rB + 2 * PL;
                float a_0 = sm[oA], a_1 = sm[oA+1], a_2 = sm[oA+2], a_3 = sm[oA+3], a_4 = sm[oA+4];
                float b_0 = sm[oB], b_1 = sm[oB+1], b_2 = sm[oB+2], b_3 = sm[oB+3], b_4 = sm[oB+4];
                wv.x = a_0+a_1+b_0+b_1; wv.y = a_1+a_2+b_1+b_2;
                wv.z = a_2+a_3+b_2+b_3; wv.w = a_3+a_4+b_3+b_4;
            }
            float i0 = wv.x > 0.f ? 1.f / wv.x : 0.f;
            float i1 = wv.y > 0.f ? 1.f / wv.y : 0.f;
            float i2 = wv.z > 0.f ? 1.f / wv.z : 0.f;
            float i3 = wv.w > 0.f ? 1.f / wv.w : 0.f;
            float4 r0, r1;
            r0.x = vx.x * i0; r0.y = vx.y * i1; r0.z = vx.z * i2; r0.w = vx.w * i3;
            r1.x = vy.x * i0; r1.y = vy.y * i1; r1.z = vy.z * i2; r1.w = vy.w * i3;
            *(float4*)(o0 + q) = r0;
            *(float4*)(o1 + q) = r1;
            *(float4*)(wp + q) = wv;           // for fixup_k renormalization
            uchar4 mk;
            mk.x = (unsigned char)(wv.x > 0.f);
            mk.y = (unsigned char)(wv.y > 0.f);
            mk.z = (unsigned char)(wv.z > 0.f);
            mk.w = (unsigned char)(wv.w > 0.f);
            *(uchar4*)(mb + q) = mk;           // q % 4 == 0 by construction
        }
    }
}

// ---------------------------------------------------------------------------
// Fixup (unchanged from R6): merge spill records into the finalized output.
// ~99% of blocks read cnt==0 and exit before any barrier (block-uniform).
// ---------------------------------------------------------------------------
__global__ __launch_bounds__(256) void fixup_k(const unsigned* __restrict__ cnt,
                                               const float4* __restrict__ buckets,
                                               float* __restrict__ out,
                                               const float* __restrict__ wplane,
                                               unsigned char* __restrict__ mask) {
    __shared__ float s[3 * 4096];      // 48 KB
    int gtile = blockIdx.x;
    unsigned n = cnt[gtile];
    if (n == 0) return;
    if (n > (unsigned)CAP) n = CAP;
    int b  = gtile / NTILE;
    int t  = gtile - b * NTILE;
    int ty = t / WT, tx = t - ty * WT;
    int X0 = tx * TILE, Y0 = ty * TILE;

    float4* s4 = (float4*)s;
    for (int i = threadIdx.x; i < 3 * 4096 / 4; i += 256)
        s4[i] = make_float4(0.f, 0.f, 0.f, 0.f);
    __syncthreads();

    const float4* bkt = buckets + (size_t)gtile * CAP;
    for (unsigned r = threadIdx.x; r < n; r += 256) {
        float4 rec = bkt[r];
        int cell = __float_as_int(rec.x);
        atomicAdd(&s[cell],        rec.y);
        atomicAdd(&s[cell + 4096], rec.z);
        atomicAdd(&s[cell + 8192], rec.w);
    }
    __syncthreads();

    float* o0 = out + (size_t)b * 2 * HWc;
    float* o1 = o0 + HWc;
    const float* wp = wplane + (size_t)b * HWc;
    unsigned char* mb = mask + (size_t)b * HWc;
    for (int cell = threadIdx.x; cell < 4096; cell += 256) {
        float ws = s[cell + 8192];
        if (ws != 0.f) {               // depth > 0.1 -> every record has w > 0
            int cy = Y0 + (cell >> 6), cx = X0 + (cell & 63);
            if (cy < HH) {
                int q = cy * WW + cx;
                float w0 = wp[q];
                float wn = w0 + ws;
                float v0 = o0[q] * w0 + s[cell];
                float v1 = o1[q] * w0 + s[cell + 4096];
                float inv = wn > 0.f ? 1.f / wn : 0.f;
                o0[q] = v0 * inv;
                o1[q] = v1 * inv;
                mb[q] = 1;
            }
        }
    }
}

// ---------------------------------------------------------------------------
// Hole fill, LDS-windowed: one block per 64x64 output core. Stage the 128x128
// mask window (core + 32 margin, zero-padded outside image) into LDS; all 4
// directional scans run as LDS byte reads (~25cyc) instead of serial global
// loads (~250cyc, 1920B-strided for up/down — this was ~280us hidden cost).
// Exact global fallback for scans exhausting the window (P ~ 0.02^32 ~ 0,
// preserves reference semantics incl. borders). Reads only filled pixels'
// values (post-fixup final), writes only holes -> race-free.
// ---------------------------------------------------------------------------
constexpr int FWW = 128;               // fill window side
__global__ __launch_bounds__(256) void fill_k(float* __restrict__ out,
                                              const unsigned char* __restrict__ mask) {
    __shared__ unsigned char wm[FWW * FWW];    // 16 KB
    const int bid  = blockIdx.x;
    const int b    = bid & 7;
    const int tile = bid >> 3;
    const int ty   = tile / WT;
    const int tx   = tile - ty * WT;
    const int X0 = tx * TILE, Y0 = ty * TILE;
    const int wx0 = X0 - 32, wy0 = Y0 - 32;
    const int tid = threadIdx.x;

    const unsigned char* mb = mask + (size_t)b * HWc;

    // stage window: thread -> (row r = tid>>1, 64B half h = tid&1)
    {
        int r  = tid >> 1, h = tid & 1;
        int wy = wy0 + r;
        int xs = wx0 + h * 64;                 // multiple of 32 -> 16B aligned
        unsigned char* dst = &wm[r * FWW + h * 64];
        if ((unsigned)wy >= (unsigned)HH) {
            uint4 z = make_uint4(0u, 0u, 0u, 0u);
            uint4* d4 = (uint4*)dst;
            d4[0] = z; d4[1] = z; d4[2] = z; d4[3] = z;
        } else if (xs >= 0 && xs + 64 <= WW) {
            const uint4* s4 = (const uint4*)(mb + (size_t)wy * WW + xs);
            uint4* d4 = (uint4*)dst;
            d4[0] = s4[0]; d4[1] = s4[1]; d4[2] = s4[2]; d4[3] = s4[3];
        } else {
            for (int i = 0; i < 64; ++i) {
                int gxx = xs + i;
                dst[i] = ((unsigned)gxx < (unsigned)WW)
                             ? mb[(size_t)wy * WW + gxx] : (unsigned char)0;
            }
        }
    }
    __syncthreads();

    const float* o0 = out + (size_t)b * 2 * HWc;
    const float* o1 = o0 + HWc;

    // 4096 core pixels / 256 threads = 16 each; wave-aligned rows.
    for (int k = 0; k < 16; ++k) {
        int ci = k * 256 + tid;
        int ry = ci >> 6, cx = ci & 63;
        int gy = Y0 + ry;
        if (gy >= HH) continue;
        int wr = ry + 32, wc = cx + 32;
        if (wm[wr * FWW + wc]) continue;       // filled -> skip

        int gxp = X0 + cx;
        float s = 0.f, s0 = 0.f, s1 = 0.f;

        // LEFT
        {
            int f = -1;
            for (int j = wc - 1; j >= 0; --j)
                if (wm[wr * FWW + j]) { f = wx0 + j; break; }
            if (f < 0 && wx0 > 0)              // exhausted window (rare)
                for (int j = wx0 - 1; j >= 0; --j)
                    if (mb[(size_t)gy * WW + j]) { f = j; break; }
            if (f >= 0) { int q = gy * WW + f; s += 1.f; s0 += o0[q]; s1 += o1[q]; }
        }
        // RIGHT (window zero-padded beyond WW -> pad never matches)
        {
            int f = -1;
            for (int j = wc + 1; j < FWW; ++j)
                if (wm[wr * FWW + j]) { f = wx0 + j; break; }
            if (f < 0 && wx0 + FWW < WW)
                for (int j = wx0 + FWW; j < WW; ++j)
                    if (mb[(size_t)gy * WW + j]) { f = j; break; }
            if (f >= 0) { int q = gy * WW + f; s += 1.f; s0 += o0[q]; s1 += o1[q]; }
        }
        // UP
        {
            int f = -1;
            for (int i = wr - 1; i >= 0; --i)
                if (wm[i * FWW + wc]) { f = wy0 + i; break; }
            if (f < 0 && wy0 > 0)
                for (int i = wy0 - 1; i >= 0; --i)
                    if (mb[(size_t)i * WW + gxp]) { f = i; break; }
            if (f >= 0) { int q = f * WW + gxp; s += 1.f; s0 += o0[q]; s1 += o1[q]; }
        }
        // DOWN (window zero-padded beyond HH -> pad never matches)
        {
            int f = -1;
            for (int i = wr + 1; i < FWW; ++i)
                if (wm[i * FWW + wc]) { f = wy0 + i; break; }
            if (f < 0 && wy0 + FWW < HH)
                for (int i = wy0 + FWW; i < HH; ++i)
                    if (mb[(size_t)i * WW + gxp]) { f = i; break; }
            if (f >= 0) { int q = f * WW + gxp; s += 1.f; s0 += o0[q]; s1 += o1[q]; }
        }

        if (s > 0.f) {
            int p = gy * WW + gxp;
            ((float*)o0)[p] = s0 / s;
            ((float*)o1)[p] = s1 / s;
        }
    }
}

extern "C" void kernel_launch(void* const* d_in, const int* in_sizes, int n_in,
                              void* d_out, int out_size, void* d_ws, size_t ws_size,
                              hipStream_t stream) {
    const float* flow  = (const float*)d_in[0];   // (B,2,H,W)
    const float* depth = (const float*)d_in[1];   // (B,1,H,W)
    float* out = (float*)d_out;                   // (B,2,H,W)

    unsigned char* wsb = (unsigned char*)d_ws;
    unsigned* cnt       = (unsigned*)wsb;
    float4*  buckets    = (float4*)(wsb + OFF_BKT);
    unsigned char* mask = wsb + OFF_MASK;
    float*   wplane     = (float*)(wsb + OFF_W);

    const int threads = 256;

    // only memset: 16 KB of spill counters
    hipMemsetAsync(cnt, 0, (size_t)GT * sizeof(unsigned), stream);

    // fused: splat + spill discovery + average + mask/w-plane
    tile_k<<<GT, 512, 0, stream>>>(flow, depth, cnt, buckets, out, mask, wplane);

    // merge rare spill records (must precede fill_k)
    fixup_k<<<GT, threads, 0, stream>>>(cnt, buckets, out, wplane, mask);

    // LDS-windowed hole fill
    fill_k<<<GT, threads, 0, stream>>>(out, mask);
}